// Round 10
// baseline (280.385 us; speedup 1.0000x reference)
//
#include <hip/hip_runtime.h>
#include <math.h>

#define B_SZ 2048
#define R_SZ 64
#define NTILE 32               // number of 64-row tiles
#define TILE 64
#define JW 32                  // J half-width per task
#define NOFF 496               // 32*31/2 tile pairs
#define KDE_BLOCKS (64 + 2 * NOFF)   // 64 diag-halves + 992 off-halves = 1056
#define FIN_BLOCKS 32          // kernel-3 blocks (one per 64-row group)

#define B_POW_NEG02 0.217637640824031f   // 2048^-0.2
#define SQRT_2PI 2.5066282746310002f
#define LOG2E 1.44269504088896340736f

// native v_exp_f32 (exp2)
extern "C" __device__ float __ocml_native_exp2_f32(float);

typedef __attribute__((ext_vector_type(2))) float f32x2;  // -> v_pk_* f32 ops

// ---------------------------------------------------------------------------
// ws layout (floats):
//   [0:256)     qsums   = per-quarter column sums   (4 x 64)
//   [256:512)   qsums2  = per-quarter column sumsq  (4 x 64)
//   [640]       ent_acc   (own 128B line)
//   [672]       done2     (int, k3 completion counter)
//   [1024:17408)          gram4 = Gram quarter-partials (64 x 4 x 64)
//   [20480:20480+8388608) parts = per-block contribution slots
//                         [32 groups][64 slots][64 rows][64 r] = 33.5 MB
// Slots per group g (all 64 written exactly once -> no zero-init needed):
//   diag (g,half):        slot = half                      (full 64 rows)
//   I-side off (g,b,half): slot = 2 + 2*(b-g-1) + half     (full 64 rows)
//   J-side off (c,g,half): slot = (64-2g) + 2*c + half     (32 rows data,
//                                                           32 rows zeros)
// ---------------------------------------------------------------------------

// Kernel 1: quarter-split stats + Gram partials + counter init.
__global__ __launch_bounds__(1024) void stats_gram_kernel(const float* __restrict__ A,
                                                          float* __restrict__ qsums,
                                                          float* __restrict__ qsums2,
                                                          float* __restrict__ gram4,
                                                          float* __restrict__ ent_acc,
                                                          int* __restrict__ done2) {
    int b = blockIdx.x;
    int i = b >> 2, qd = b & 3;
    int tid = threadIdx.x;
    int j = tid & 63, bg = tid >> 6;          // 16 b-groups

    const float* __restrict__ Aq = A + (qd * 512) * R_SZ;
    float g = 0.f, sj = 0.f, s2j = 0.f;
#pragma unroll 4
    for (int t = bg; t < 512; t += 16) {
        float ai = Aq[t * R_SZ + i];          // wave-uniform broadcast
        float aj = Aq[t * R_SZ + j];          // coalesced 256B/wave
        g = fmaf(ai, aj, g);
        sj += aj;
        s2j = fmaf(aj, aj, s2j);
    }

    __shared__ float gred[16][64], sred[16][64], s2red[16][64];
    gred[bg][j] = g; sred[bg][j] = sj; s2red[bg][j] = s2j;
    __syncthreads();
    if (tid < 64) {
        float G = 0.f, S = 0.f, S2 = 0.f;
#pragma unroll
        for (int t = 0; t < 16; ++t) { G += gred[t][j]; S += sred[t][j]; S2 += s2red[t][j]; }
        gram4[b * 64 + j] = G;                // quarter-partial of gram row i
        if (i == 0) {                         // one writer set per quarter
            qsums[qd * 64 + j]  = S;
            qsums2[qd * 64 + j] = S2;
        }
    }
    if (b == 0 && tid == 512) { *ent_acc = 0.f; *done2 = 0; }
}

// ---------------------------------------------------------------------------
// Kernel 2: SYMMETRIC pairwise KDE — pure accumulate, NO global atomics.
// Round-9 diagnosis: 25 MB of device-scope atomicAdd ran at ~140 GB/s
// (memory-side atomic ceiling on 8-XCD) = the whole 180us. This version
// writes each block's contribution to a PRIVATE slot with plain coalesced
// stores; kernel 3 reduces the slots. Only atomics left: LDS ds_add (CU-
// local, staggered contention-free walk) and the k3 tail counters.
// ---------------------------------------------------------------------------
__global__ __launch_bounds__(1024, 4) void kde_kernel(const float* __restrict__ A,
                                                      const float* __restrict__ qsums,
                                                      const float* __restrict__ qsums2,
                                                      float* __restrict__ parts) {
    int tid = threadIdx.x;
    int r = tid & 63, sg = tid >> 6;

    __shared__ float k0s[64];
    __shared__ float ldsJ[JW][64];            // J-side partial sums (8 KB)

    // zero ldsJ (2048 floats, 2 per thread)
    ((float*)ldsJ)[tid] = 0.f;
    ((float*)ldsJ)[tid + 1024] = 0.f;

    // ---- prologue: bandwidth per receptor from quarter sums ----
    if (tid < 64) {
        float S  = qsums[tid]  + qsums[64 + tid]  + qsums[128 + tid]  + qsums[192 + tid];
        float S2 = qsums2[tid] + qsums2[64 + tid] + qsums2[128 + tid] + qsums2[192 + tid];
        float m = S * (1.f / (float)B_SZ);
        float var = (S2 - S * m) * (1.f / (float)(B_SZ - 1));   // ddof=1
        var = fmaxf(var, 0.f);
        float h = fmaxf(1.06f * sqrtf(var) * B_POW_NEG02, 1e-4f);
        k0s[tid] = sqrtf(0.5f * LOG2E) / h;   // exp2(-(k*d)^2) = exp(-0.5(d/h)^2)
    }
    __syncthreads();                          // also orders ldsJ zeroing
    float k0 = k0s[r];

    // ---- task decode (wave-uniform scalar work; loop bounded: a < 32) ----
    int a, bT, half, isoff;
    {
        int bid = blockIdx.x;
        if (bid < 64) { a = bid >> 1; bT = a; half = bid & 1; isoff = 0; }
        else {
            int t = bid - 64; int p = t >> 1; half = t & 1; isoff = 1;
            int len = NTILE - 1; a = 0;
            while (p >= len && len > 0) { p -= len; --len; ++a; }
            bT = a + 1 + p;
        }
    }
    int Jbase = bT * TILE + half * JW;

    int i0 = a * TILE + sg * 4;               // this wave's 4 I-rows
    f32x2 uq01 = { A[(i0 + 0) * R_SZ + r] * k0, A[(i0 + 1) * R_SZ + r] * k0 };
    f32x2 uq23 = { A[(i0 + 2) * R_SZ + r] * k0, A[(i0 + 3) * R_SZ + r] * k0 };
    f32x2 c01 = { 0.f, 0.f }, c23 = { 0.f, 0.f };

    const float* __restrict__ Ap = A + Jbase * R_SZ + r;

#define KDE_CORE(usv)                                                          \
        f32x2 uss = { (usv), (usv) };                                          \
        f32x2 d01 = uq01 - uss, d23 = uq23 - uss;                              \
        f32x2 n01 = -d01 * d01, n23 = -d23 * d23;                              \
        f32x2 e01 = { __ocml_native_exp2_f32(n01.x), __ocml_native_exp2_f32(n01.y) }; \
        f32x2 e23 = { __ocml_native_exp2_f32(n23.x), __ocml_native_exp2_f32(n23.y) }; \
        c01 += e01; c23 += e23;

    if (!isoff) {
        // ---- diagonal half-tile: I-side only, sequential 32-sample walk ----
        float p[4];
#pragma unroll
        for (int j = 0; j < 4; ++j) p[j] = Ap[j * 64];
        int li = 4 * 64;
#pragma unroll 1
        for (int k = 0; k < 7; ++k) {                  // 7 x 4 = 28 consumed
#pragma unroll
            for (int j = 0; j < 4; ++j) {
                float us = p[j] * k0;
                p[j] = Ap[li + j * 64];
                KDE_CORE(us)
            }
            li += 4 * 64;
        }
#pragma unroll
        for (int j = 0; j < 4; ++j) {
            float us = p[j] * k0;
            KDE_CORE(us)
        }
    } else {
        // ---- off-diag half-tile: staggered walk + J-side LDS accumulate ----
        int j0 = sg * 2;                      // 16 distinct starts (0,2,..,30)
        float p[4];
#pragma unroll
        for (int j = 0; j < 4; ++j) p[j] = Ap[((j0 + j) & 31) * 64];
#pragma unroll 1
        for (int k = 0; k < 7; ++k) {
#pragma unroll
            for (int j = 0; j < 4; ++j) {
                float us = p[j] * k0;
                p[j] = Ap[((j0 + k * 4 + j + 4) & 31) * 64];
                int jj = (j0 + k * 4 + j) & 31;
                KDE_CORE(us)
                float jp = (e01.x + e01.y) + (e23.x + e23.y);
                atomicAdd(&ldsJ[jj][r], jp);  // ds_add, contention-free walk
            }
        }
#pragma unroll
        for (int j = 0; j < 4; ++j) {
            float us = p[j] * k0;
            int jj = (j0 + 28 + j) & 31;
            KDE_CORE(us)
            float jp = (e01.x + e01.y) + (e23.x + e23.y);
            atomicAdd(&ldsJ[jj][r], jp);
        }
    }
#undef KDE_CORE

    // ---- I-side: plain coalesced stores into this block's private slot ----
    int islot = isoff ? (2 + 2 * (bT - a - 1) + half) : half;
    float* __restrict__ ip = parts + ((a * 64 + islot) << 12) + (sg * 4) * 64 + r;
    ip[0]   = c01.x;
    ip[64]  = c01.y;
    ip[128] = c23.x;
    ip[192] = c23.y;

    __syncthreads();                          // LDS atomics visible
    if (isoff) {                              // J-side slot: 32 rows + zeros
        int jslot = (64 - 2 * bT) + 2 * a + half;
        float* __restrict__ jp = parts + ((bT * 64 + jslot) << 12);
#pragma unroll
        for (int j = 0; j < 4; ++j) {
            int row = sg + j * 16;            // 0..63
            int jr = row - half * JW;
            float val = (jr >= 0 && jr < JW) ? ldsJ[jr][r] : 0.f;
            jp[row * 64 + r] = val;
        }
    }
}

// ---------------------------------------------------------------------------
// Kernel 3: slot reduction + entropy + covariance finish. 32 blocks x 1024;
// block g sums its 64 slots (1 MB, coalesced, 4-way ILP), takes logs, then
// the proven single-counter tail folds the covariance penalty.
// ---------------------------------------------------------------------------
__global__ __launch_bounds__(1024) void finish_kernel(const float* __restrict__ qsums,
                                                      const float* __restrict__ qsums2,
                                                      const float* __restrict__ gram4,
                                                      const float* __restrict__ parts,
                                                      float* __restrict__ ent_acc,
                                                      int* __restrict__ done2,
                                                      float* __restrict__ out) {
    int tid = threadIdx.x;
    int r = tid & 63, sg = tid >> 6;
    int g = blockIdx.x;

    __shared__ float lscs[64], sums_s[64];
    __shared__ float wred[16];
    if (tid < 64) {
        float S  = qsums[tid]  + qsums[64 + tid]  + qsums[128 + tid]  + qsums[192 + tid];
        float S2 = qsums2[tid] + qsums2[64 + tid] + qsums2[128 + tid] + qsums2[192 + tid];
        float m = S * (1.f / (float)B_SZ);
        float var = (S2 - S * m) * (1.f / (float)(B_SZ - 1));   // ddof=1
        var = fmaxf(var, 0.f);
        float h = fmaxf(1.06f * sqrtf(var) * B_POW_NEG02, 1e-4f);
        lscs[tid] = 1.0f / ((float)B_SZ * h * SQRT_2PI);
        sums_s[tid] = S;
    }
    __syncthreads();

    const float* __restrict__ gbase = parts + (g * 64) * 4096;
    float v = 0.f;
#pragma unroll
    for (int j = 0; j < 4; ++j) {
        int row = sg + j * 16;                // 0..63
        const float* __restrict__ p0 = gbase + row * 64 + r;
        float S0 = 0.f, S1 = 0.f, S2 = 0.f, S3 = 0.f;
#pragma unroll 4
        for (int s = 0; s < 64; s += 4) {     // 64 slots, stride 16 KB
            S0 += p0[(s + 0) << 12];
            S1 += p0[(s + 1) << 12];
            S2 += p0[(s + 2) << 12];
            S3 += p0[(s + 3) << 12];
        }
        float S = (S0 + S1) + (S2 + S3);
        v += __logf(fmaf(S, lscs[r], 1e-8f));
    }
    for (int off = 32; off > 0; off >>= 1) v += __shfl_down(v, off, 64);
    if (r == 0) wred[sg] = v;
    __syncthreads();

    __shared__ int lastflag;
    if (tid == 0) {
        float p2 = 0.f;
#pragma unroll
        for (int t = 0; t < 16; ++t) p2 += wred[t];
        p2 *= (1.0f / ((float)B_SZ * (float)R_SZ));
        atomicAdd(ent_acc, p2);               // once per block
        __threadfence();
        int prev = atomicAdd(done2, 1);
        lastflag = (prev == FIN_BLOCKS - 1);
    }
    __syncthreads();
    if (lastflag) {                           // grid-final: covariance fold
        __threadfence();
        float v2 = 0.f;
#pragma unroll
        for (int c = tid; c < 4096; c += 1024) {
            int ii = c >> 6, jj = c & 63;     // ii wave-uniform, jj = lane
            const float* gp = gram4 + ii * 256 + jj;
            float G = gp[0] + gp[64] + gp[128] + gp[192];
            float mi = sums_s[ii] * (1.f / (float)B_SZ);
            float mj = sums_s[jj] * (1.f / (float)B_SZ);
            float cov = (G - (float)B_SZ * mi * mj) * (1.f / (float)(B_SZ - 1));
            if (ii != jj) v2 = fmaf(cov, cov, v2);
        }
        for (int off = 32; off > 0; off >>= 1) v2 += __shfl_down(v2, off, 64);
        __shared__ float wsum[16];
        if (r == 0) wsum[sg] = v2;
        __syncthreads();
        if (tid == 0) {
            float C = 0.f;
#pragma unroll
            for (int t = 0; t < 16; ++t) C += wsum[t];
            float ent = __hip_atomic_load(ent_acc, __ATOMIC_ACQUIRE,
                                          __HIP_MEMORY_SCOPE_AGENT);
            out[0] = ent + C;                 // COV_WEIGHT = 1.0
        }
    }
}

extern "C" void kernel_launch(void* const* d_in, const int* in_sizes, int n_in,
                              void* d_out, int out_size, void* d_ws, size_t ws_size,
                              hipStream_t stream) {
    const float* A = (const float*)d_in[0];
    float* out = (float*)d_out;

    float* wsf = (float*)d_ws;
    float* qsums   = wsf;                // 256
    float* qsums2  = wsf + 256;          // 256
    float* ent_acc = wsf + 640;          // isolated cache line
    int*   done2   = (int*)(wsf + 672);
    float* gram4   = wsf + 1024;         // 64 rows x 4 quarters x 64
    float* parts   = wsf + 20480;        // [32][64][64][64] slots, 33.5 MB

    stats_gram_kernel<<<256, 1024, 0, stream>>>(A, qsums, qsums2, gram4,
                                                ent_acc, done2);
    kde_kernel<<<KDE_BLOCKS, 1024, 0, stream>>>(A, qsums, qsums2, parts);
    finish_kernel<<<FIN_BLOCKS, 1024, 0, stream>>>(qsums, qsums2, gram4, parts,
                                                   ent_acc, done2, out);
}

// Round 11
// 101.357 us; speedup vs baseline: 2.7663x; 2.7663x over previous
//
#include <hip/hip_runtime.h>
#include <math.h>

#define B_SZ 2048
#define R_SZ 64
#define QT 4                    // q rows per kde block (low VGPR pressure)
#define KDE_BLOCKS (B_SZ / QT)  // 512 blocks * 16 waves

#define B_POW_NEG02 0.217637640824031f   // 2048^-0.2 = 2^-2.2
#define SQRT_2PI 2.5066282746310002f
#define LOG2E 1.44269504088896340736f

// native v_exp_f32 (exp2)
extern "C" __device__ float __ocml_native_exp2_f32(float);

typedef __attribute__((ext_vector_type(2))) float f32x2;

// ---------------------------------------------------------------------------
// ws layout (floats):
//   [0:256)     qsums   = per-quarter column sums   (4 x 64)
//   [256:512)   qsums2  = per-quarter column sumsq  (4 x 64)
//   [640]       ent_acc   (own 128B line)
//   [672]       done_cnt  (int, own line)
//   [1024:17408)  gram4 = Gram quarter-partials (64 rows x 4 qtr x 64)
// ---------------------------------------------------------------------------

// Kernel 1: quarter-split stats + Gram partials. 256 blocks (i = b>>2 gram
// row, qd = b&3 -> rows [qd*512, qd*512+512)). All 256 CUs active.
__global__ __launch_bounds__(1024) void stats_gram_kernel(const float* __restrict__ A,
                                                          float* __restrict__ qsums,
                                                          float* __restrict__ qsums2,
                                                          float* __restrict__ gram4,
                                                          float* __restrict__ ent_acc,
                                                          int* __restrict__ done_cnt) {
    int b = blockIdx.x;
    int i = b >> 2, qd = b & 3;
    int tid = threadIdx.x;
    int j = tid & 63, bg = tid >> 6;          // 16 b-groups

    const float* __restrict__ Aq = A + (qd * 512) * R_SZ;
    float g = 0.f, sj = 0.f, s2j = 0.f;
#pragma unroll 4
    for (int t = bg; t < 512; t += 16) {
        float ai = Aq[t * R_SZ + i];          // wave-uniform broadcast
        float aj = Aq[t * R_SZ + j];          // coalesced 256B/wave
        g = fmaf(ai, aj, g);
        sj += aj;
        s2j = fmaf(aj, aj, s2j);
    }

    __shared__ float gred[16][64], sred[16][64], s2red[16][64];
    gred[bg][j] = g; sred[bg][j] = sj; s2red[bg][j] = s2j;
    __syncthreads();
    if (tid < 64) {
        float G = 0.f, S = 0.f, S2 = 0.f;
#pragma unroll
        for (int t = 0; t < 16; ++t) { G += gred[t][j]; S += sred[t][j]; S2 += s2red[t][j]; }
        gram4[b * 64 + j] = G;                // quarter-partial of gram row i
        if (i == 0) {                         // one writer set per quarter
            qsums[qd * 64 + j]  = S;
            qsums2[qd * 64 + j] = S2;
        }
    }
    if (b == 0 && tid == 64) { *ent_acc = 0.f; *done_cnt = 0; }
}

// ---------------------------------------------------------------------------
// Kernel 2: pairwise KDE, QT=4, 512 blocks x 1024 thr. Each block owns 4
// query rows and streams ALL 2048 samples (wave sg: s = sg + 16k, k=0..127,
// 8-deep register prefetch). VGPR ~32, no spill. Issue-port-bound on
// v_exp_f32 (~8 cyc each, no separate trans pipe): 14 cyc/element-kernel
// exact-form floor -> ~48.6us model, 50.6us measured (R5). Occupancy-
// invariant (R2 vs R5) — do not trade structure for waves.
// ---------------------------------------------------------------------------
__global__ __launch_bounds__(1024) void kde_kernel(const float* __restrict__ A,
                                                   const float* __restrict__ qsums,
                                                   const float* __restrict__ qsums2,
                                                   const float* __restrict__ gram4,
                                                   float* __restrict__ ent_acc,
                                                   int* __restrict__ done_cnt,
                                                   float* __restrict__ out) {
    int tid = threadIdx.x;
    int r = tid & 63, sg = tid >> 6;

    // ---- prologue: bandwidth per receptor from quarter sums ----
    __shared__ float k0s[64], lscs[64], sums_s[64];
    if (tid < 64) {
        float S  = qsums[tid]  + qsums[64 + tid]  + qsums[128 + tid]  + qsums[192 + tid];
        float S2 = qsums2[tid] + qsums2[64 + tid] + qsums2[128 + tid] + qsums2[192 + tid];
        float m = S * (1.f / (float)B_SZ);
        float var = (S2 - S * m) * (1.f / (float)(B_SZ - 1));   // ddof=1
        var = fmaxf(var, 0.f);
        float h = fmaxf(1.06f * sqrtf(var) * B_POW_NEG02, 1e-4f);
        k0s[tid]  = sqrtf(0.5f * LOG2E) / h;  // exp2(-(k*d)^2) = exp(-0.5(d/h)^2)
        lscs[tid] = 1.0f / ((float)B_SZ * h * SQRT_2PI);
        sums_s[tid] = S;
    }
    __syncthreads();
    float k0 = k0s[r];

    int q0 = blockIdx.x * QT;
    f32x2 uq01 = { A[(q0 + 0) * R_SZ + r] * k0, A[(q0 + 1) * R_SZ + r] * k0 };
    f32x2 uq23 = { A[(q0 + 2) * R_SZ + r] * k0, A[(q0 + 3) * R_SZ + r] * k0 };
    f32x2 c01 = { 0.f, 0.f }, c23 = { 0.f, 0.f };

#define KDE_BODY(usv)                                                          \
    {                                                                          \
        f32x2 uss = { (usv), (usv) };                                          \
        f32x2 d01 = uq01 - uss, d23 = uq23 - uss;                              \
        f32x2 n01 = -d01 * d01, n23 = -d23 * d23;                              \
        f32x2 e01 = { __ocml_native_exp2_f32(n01.x), __ocml_native_exp2_f32(n01.y) }; \
        f32x2 e23 = { __ocml_native_exp2_f32(n23.x), __ocml_native_exp2_f32(n23.y) }; \
        c01 += e01; c23 += e23;                                                \
    }

    // wave sg consumes s = sg + 16k, k = 0..127; element stride 16*64 = 1024
    const float* __restrict__ Ap = A + sg * R_SZ + r;
    float p[8];
#pragma unroll
    for (int j = 0; j < 8; ++j) p[j] = Ap[j * 1024];   // prologue: 8 in flight

    int li = 8 * 1024;
#pragma unroll 1
    for (int k = 0; k < 15; ++k) {                     // 15 x 8 = 120 consumed
#pragma unroll
        for (int j = 0; j < 8; ++j) {
            float us = p[j] * k0;                      // on-the-fly prescale
            p[j] = Ap[li + j * 1024];                  // prefetch k+8 group
            KDE_BODY(us);
        }
        li += 8 * 1024;
    }
#pragma unroll
    for (int j = 0; j < 8; ++j) { float us = p[j] * k0; KDE_BODY(us); }

#undef KDE_BODY

    // cross-wave reduction of the 4 query-row densities (16 KB LDS)
    __shared__ float red[16][QT][64];
    red[sg][0][r] = c01.x; red[sg][1][r] = c01.y;
    red[sg][2][r] = c23.x; red[sg][3][r] = c23.y;
    __syncthreads();
    __shared__ float wred[QT];
    if (sg < QT) {                             // wave sg owns query row sg
        float S = 0.f;
#pragma unroll
        for (int t = 0; t < 16; ++t) S += red[t][sg][r];
        float v = __logf(fmaf(S, lscs[r], 1e-8f));
        for (int off = 32; off > 0; off >>= 1) v += __shfl_down(v, off, 64);
        if (r == 0) wred[sg] = v;
    }
    __syncthreads();
    __shared__ int lastflag;
    if (tid == 0) {
        float p2 = 0.f;
#pragma unroll
        for (int t = 0; t < QT; ++t) p2 += wred[t];
        p2 *= (1.0f / ((float)B_SZ * (float)R_SZ));
        atomicAdd(ent_acc, p2);                // once per block
        __threadfence();
        int prev = atomicAdd(done_cnt, 1);
        lastflag = (prev == KDE_BLOCKS - 1);
    }
    __syncthreads();
    if (lastflag) {                            // grid-final fold in last block
        __threadfence();
        float v = 0.f;
#pragma unroll
        for (int c = tid; c < 4096; c += 1024) {
            int ii = c >> 6, jj = c & 63;      // ii wave-uniform, jj = lane
            const float* gp = gram4 + ii * 256 + jj;
            float G = gp[0] + gp[64] + gp[128] + gp[192];
            float mi = sums_s[ii] * (1.f / (float)B_SZ);
            float mj = sums_s[jj] * (1.f / (float)B_SZ);
            float cov = (G - (float)B_SZ * mi * mj) * (1.f / (float)(B_SZ - 1));
            if (ii != jj) v = fmaf(cov, cov, v);
        }
        for (int off = 32; off > 0; off >>= 1) v += __shfl_down(v, off, 64);
        __shared__ float wsum[16];
        if (r == 0) wsum[sg] = v;
        __syncthreads();
        if (tid == 0) {
            float C = 0.f;
#pragma unroll
            for (int t = 0; t < 16; ++t) C += wsum[t];
            float ent = __hip_atomic_load(ent_acc, __ATOMIC_ACQUIRE,
                                          __HIP_MEMORY_SCOPE_AGENT);
            out[0] = ent + C;                  // COV_WEIGHT = 1.0
        }
    }
}

extern "C" void kernel_launch(void* const* d_in, const int* in_sizes, int n_in,
                              void* d_out, int out_size, void* d_ws, size_t ws_size,
                              hipStream_t stream) {
    const float* A = (const float*)d_in[0];
    float* out = (float*)d_out;

    float* wsf = (float*)d_ws;
    float* qsums   = wsf;                // 256
    float* qsums2  = wsf + 256;          // 256
    float* ent_acc = wsf + 640;          // isolated cache line
    int*   done_cnt = (int*)(wsf + 672);
    float* gram4   = wsf + 1024;         // 64 rows x 4 quarters x 64

    stats_gram_kernel<<<R_SZ * 4, 1024, 0, stream>>>(A, qsums, qsums2, gram4,
                                                     ent_acc, done_cnt);
    kde_kernel<<<KDE_BLOCKS, 1024, 0, stream>>>(A, qsums, qsums2, gram4,
                                                ent_acc, done_cnt, out);
}